// Round 1
// baseline (1181.966 us; speedup 1.0000x reference)
//
#include <hip/hip_runtime.h>
#include <hip/hip_bf16.h>
#include <cstdint>

// Performer (FAVOR+) non-causal attention, fp32.
// B=4 S=4096 D=512 H=8 KD=64 R=256.
constexpr int B = 4, S = 4096, D = 512, H = 8, KD = 64, R = 256;
constexpr int M = B * S;          // 16384 rows
constexpr float EPS = 1e-3f;
constexpr float SCALE = 0.125f;   // 1/sqrt(KD)
constexpr int NCH = 16;           // S-chunks for kv partial accumulation
constexpr int CHS = S / NCH;      // 256

// ws layout (float offsets)
constexpr size_t OFF_Q     = 0;          // 8388608
constexpr size_t OFF_K     = 8388608;    // 8388608 (reused as attn later)
constexpr size_t OFF_V     = 16777216;   // 8388608
constexpr size_t OFF_RFT   = 25165824;   // 16384   rf^T * SCALE, [d][r]
constexpr size_t OFF_KVP   = 25182208;   // 8388608 partial kv
constexpr size_t OFF_KSUMP = 33570816;   // 131072  partial ksum
constexpr size_t OFF_KVT   = 33701888;   // 524288  kv in [r/4][d][r%4] layout
constexpr size_t OFF_KSUM  = 34226176;   // 8192
// total ~34.24M floats = ~137 MB

__device__ __forceinline__ float bcast(float x, int lane) {
  return __int_as_float(__builtin_amdgcn_readlane(__float_as_int(x), lane));
}

// rft[d*256 + r] = rf[r*64 + d] * SCALE
__global__ __launch_bounds__(256) void rft_kernel(const float* __restrict__ rf,
                                                  float* __restrict__ rft) {
  int i = blockIdx.x * 256 + threadIdx.x;  // 16384
  int dd = i >> 8, rr = i & 255;
  rft[i] = rf[rr * KD + dd] * SCALE;
}

// C[M x 512] = A[M x 512] @ W[512 x 512] (+ bias). 128x128 tile, 8x8 micro.
template <bool BIAS>
__global__ __launch_bounds__(256) void gemm512(const float* __restrict__ A,
                                               const float* __restrict__ W,
                                               const float* __restrict__ bias,
                                               float* __restrict__ C) {
  __shared__ alignas(16) float As[16][132];  // [k][m], padded stride
  __shared__ alignas(16) float Bs[16][128];  // [k][n]
  const int t = threadIdx.x;
  const int bm = (int)(blockIdx.x >> 2) * 128;
  const int bn = (int)(blockIdx.x & 3) * 128;
  const int tr = t >> 4, tc = t & 15;
  const int arow = t >> 2, akq = (t & 3) * 4;
  const int bk = t >> 5, bc = (t & 31) * 4;
  float acc[8][8] = {};
  for (int k0 = 0; k0 < 512; k0 += 16) {
    float4 a0 = *(const float4*)&A[(size_t)(bm + arow) * 512 + k0 + akq];
    float4 a1 = *(const float4*)&A[(size_t)(bm + arow + 64) * 512 + k0 + akq];
    float4 b0 = *(const float4*)&W[(size_t)(k0 + bk) * 512 + bn + bc];
    float4 b1 = *(const float4*)&W[(size_t)(k0 + bk + 8) * 512 + bn + bc];
    __syncthreads();  // prev iteration's LDS reads complete
    As[akq + 0][arow] = a0.x; As[akq + 1][arow] = a0.y;
    As[akq + 2][arow] = a0.z; As[akq + 3][arow] = a0.w;
    As[akq + 0][arow + 64] = a1.x; As[akq + 1][arow + 64] = a1.y;
    As[akq + 2][arow + 64] = a1.z; As[akq + 3][arow + 64] = a1.w;
    *(float4*)&Bs[bk][bc] = b0;
    *(float4*)&Bs[bk + 8][bc] = b1;
    __syncthreads();
#pragma unroll
    for (int k = 0; k < 16; ++k) {
      float4 x0 = *(const float4*)&As[k][tr * 8];
      float4 x1 = *(const float4*)&As[k][tr * 8 + 4];
      float4 y0 = *(const float4*)&Bs[k][tc * 8];
      float4 y1 = *(const float4*)&Bs[k][tc * 8 + 4];
      float av[8] = {x0.x, x0.y, x0.z, x0.w, x1.x, x1.y, x1.z, x1.w};
      float bv[8] = {y0.x, y0.y, y0.z, y0.w, y1.x, y1.y, y1.z, y1.w};
#pragma unroll
      for (int i = 0; i < 8; ++i)
#pragma unroll
        for (int j = 0; j < 8; ++j) acc[i][j] = fmaf(av[i], bv[j], acc[i][j]);
    }
  }
#pragma unroll
  for (int i = 0; i < 8; ++i) {
    size_t row = (size_t)(bm + tr * 8 + i);
#pragma unroll
    for (int j4 = 0; j4 < 2; ++j4) {
      int col = bn + tc * 8 + j4 * 4;
      float4 o;
      o.x = acc[i][j4 * 4 + 0]; o.y = acc[i][j4 * 4 + 1];
      o.z = acc[i][j4 * 4 + 2]; o.w = acc[i][j4 * 4 + 3];
      if (BIAS) {
        o.x += bias[col + 0]; o.y += bias[col + 1];
        o.z += bias[col + 2]; o.w += bias[col + 3];
      }
      *(float4*)&C[row * 512 + col] = o;
    }
  }
}

// Per (b,h,chunk): kvp[r][d] = sum_s kf(s,r)*v(s,d); ksump[r] = sum_s kf(s,r).
// kf computed on the fly: proj = (k_row . rf_r)*SCALE, blockmax over r, exp+EPS.
__global__ __launch_bounds__(256) void kv_partial(const float* __restrict__ kbuf,
                                                  const float* __restrict__ vbuf,
                                                  const float* __restrict__ rft,
                                                  float* __restrict__ kvp,
                                                  float* __restrict__ ksump) {
  __shared__ alignas(16) float rowbuf[2][128];  // [slot][ k(64) | v(64) ]
  __shared__ float maxbuf[2][4];
  const int t = threadIdx.x;       // t == r
  const int bid = blockIdx.x;      // B*H*NCH
  const int ch = bid & (NCH - 1);
  const int bh = bid / NCH;
  const int b = bh >> 3, h = bh & 7;
  const int lane = t & 63, w = t >> 6;
  float rfreg[64];
#pragma unroll
  for (int d = 0; d < 64; ++d) rfreg[d] = rft[d * 256 + t];  // pre-scaled
  float acc[64] = {};
  float ksacc = 0.f;
  const size_t base = (size_t)(b * S + ch * CHS) * 512 + h * 64;
  const float* krow = kbuf + base;
  const float* vrow = vbuf + base;
  for (int s = 0; s < CHS; ++s) {
    const int sl = s & 1;
    if (t < 128) {
      rowbuf[sl][t] = (t < 64) ? krow[(size_t)s * 512 + t]
                               : vrow[(size_t)s * 512 + (t - 64)];
    }
    __syncthreads();
    float proj = 0.f;
#pragma unroll
    for (int d4 = 0; d4 < 16; ++d4) {
      float4 kk = *(const float4*)&rowbuf[sl][d4 * 4];
      proj = fmaf(kk.x, rfreg[d4 * 4 + 0], proj);
      proj = fmaf(kk.y, rfreg[d4 * 4 + 1], proj);
      proj = fmaf(kk.z, rfreg[d4 * 4 + 2], proj);
      proj = fmaf(kk.w, rfreg[d4 * 4 + 3], proj);
    }
    float m2 = proj;
#pragma unroll
    for (int off = 32; off > 0; off >>= 1) m2 = fmaxf(m2, __shfl_xor(m2, off));
    if (lane == 0) maxbuf[sl][w] = m2;
    __syncthreads();
    float mm = fmaxf(fmaxf(maxbuf[sl][0], maxbuf[sl][1]),
                     fmaxf(maxbuf[sl][2], maxbuf[sl][3]));
    float kf = __expf(proj - mm) + EPS;
    ksacc += kf;
#pragma unroll
    for (int d4 = 0; d4 < 16; ++d4) {
      float4 vv = *(const float4*)&rowbuf[sl][64 + d4 * 4];
      acc[d4 * 4 + 0] = fmaf(kf, vv.x, acc[d4 * 4 + 0]);
      acc[d4 * 4 + 1] = fmaf(kf, vv.y, acc[d4 * 4 + 1]);
      acc[d4 * 4 + 2] = fmaf(kf, vv.z, acc[d4 * 4 + 2]);
      acc[d4 * 4 + 3] = fmaf(kf, vv.w, acc[d4 * 4 + 3]);
    }
  }
  float4* o = (float4*)&kvp[((size_t)bid * R + t) * KD];
#pragma unroll
  for (int d4 = 0; d4 < 16; ++d4)
    o[d4] = make_float4(acc[4 * d4], acc[4 * d4 + 1], acc[4 * d4 + 2], acc[4 * d4 + 3]);
  ksump[(size_t)bid * R + t] = ksacc;
}

// Reduce NCH partials; write kv in transposed-interleaved layout for attn kernel:
// kvt[bh][ (r>>2)*256 + d*4 + (r&3) ] = kv[bh][r][d]
__global__ __launch_bounds__(256) void kv_reduce(const float* __restrict__ kvp,
                                                 const float* __restrict__ ksump,
                                                 float* __restrict__ kvt,
                                                 float* __restrict__ ksum) {
  const int i = blockIdx.x * 256 + threadIdx.x;  // 524288
  const int bh = i >> 14;
  const int rd = i & 16383;
  const int r = rd >> 6, dd = rd & 63;
  float s = 0.f;
#pragma unroll
  for (int c = 0; c < NCH; ++c) s += kvp[(((size_t)(bh * NCH + c)) << 14) + rd];
  kvt[((size_t)bh << 14) + (size_t)(r >> 2) * 256 + dd * 4 + (r & 3)] = s;
  if (i < B * H * R) {
    const int bh2 = i >> 8, r2 = i & 255;
    float ss = 0.f;
#pragma unroll
    for (int c = 0; c < NCH; ++c) ss += ksump[(size_t)(bh2 * NCH + c) * R + r2];
    ksum[i] = ss;
  }
}

// attn[b,s,h,:] = (qf . kv) / (qf . ksum + EPS); qf computed on the fly.
// One wave per 4 s-rows; lane owns output d; lane also owns r=4*lane+i for qf.
__global__ __launch_bounds__(256) void attn_num(const float* __restrict__ q,
                                                const float* __restrict__ rft,
                                                const float* __restrict__ kvt,
                                                const float* __restrict__ ksum,
                                                float* __restrict__ attn) {
  __shared__ alignas(16) float kvl[R * KD];  // 64KB
  __shared__ alignas(16) float ksl[R];
  const int t = threadIdx.x, lane = t & 63, w = t >> 6;
  const int bid = blockIdx.x;               // B*H*(S/256) = 512
  const int bh = bid >> 4, ch = bid & 15;
  const int b = bh >> 3, h = bh & 7;
  const float* kvsrc = kvt + ((size_t)bh << 14);
#pragma unroll
  for (int it = 0; it < 16; ++it) {
    int i = t * 4 + it * 1024;
    *(float4*)&kvl[i] = *(const float4*)&kvsrc[i];
  }
  ksl[t] = ksum[bh * R + t];
  __syncthreads();
  float ks4[4];
  {
    float4 kk = *(const float4*)&ksl[lane * 4];
    ks4[0] = kk.x; ks4[1] = kk.y; ks4[2] = kk.z; ks4[3] = kk.w;
  }
  const int sbase = ch * 256 + w * 64;
  for (int g = 0; g < 16; ++g) {
    const int s = sbase + g * 4;
    const float* qbase = q + (size_t)(b * S + s) * 512 + h * 64 + lane;
    float qv[4];
#pragma unroll
    for (int ts = 0; ts < 4; ++ts) qv[ts] = qbase[(size_t)ts * 512];
    float pj[4][4] = {};
#pragma unroll
    for (int d = 0; d < 64; ++d) {
      float4 rfv = *(const float4*)&rft[d * 256 + lane * 4];
#pragma unroll
      for (int ts = 0; ts < 4; ++ts) {
        float qd = bcast(qv[ts], d);
        pj[ts][0] = fmaf(qd, rfv.x, pj[ts][0]);
        pj[ts][1] = fmaf(qd, rfv.y, pj[ts][1]);
        pj[ts][2] = fmaf(qd, rfv.z, pj[ts][2]);
        pj[ts][3] = fmaf(qd, rfv.w, pj[ts][3]);
      }
    }
    float qf[4][4], rden[4];
#pragma unroll
    for (int ts = 0; ts < 4; ++ts) {
      float m2 = fmaxf(fmaxf(pj[ts][0], pj[ts][1]), fmaxf(pj[ts][2], pj[ts][3]));
#pragma unroll
      for (int off = 32; off > 0; off >>= 1) m2 = fmaxf(m2, __shfl_xor(m2, off));
      float dacc = 0.f;
#pragma unroll
      for (int i = 0; i < 4; ++i) {
        qf[ts][i] = __expf(pj[ts][i] - m2) + EPS;
        dacc = fmaf(qf[ts][i], ks4[i], dacc);
      }
#pragma unroll
      for (int off = 32; off > 0; off >>= 1) dacc += __shfl_xor(dacc, off);
      rden[ts] = 1.0f / (dacc + EPS);
    }
    float num[4] = {0.f, 0.f, 0.f, 0.f};
#pragma unroll 8
    for (int r4 = 0; r4 < 64; ++r4) {
      float4 kvv = *(const float4*)&kvl[r4 * 256 + lane * 4];
#pragma unroll
      for (int ts = 0; ts < 4; ++ts) {
        num[ts] = fmaf(bcast(qf[ts][0], r4), kvv.x, num[ts]);
        num[ts] = fmaf(bcast(qf[ts][1], r4), kvv.y, num[ts]);
        num[ts] = fmaf(bcast(qf[ts][2], r4), kvv.z, num[ts]);
        num[ts] = fmaf(bcast(qf[ts][3], r4), kvv.w, num[ts]);
      }
    }
    float* obase = attn + (size_t)(b * S + s) * 512 + h * 64 + lane;
#pragma unroll
    for (int ts = 0; ts < 4; ++ts) obase[(size_t)ts * 512] = num[ts] * rden[ts];
  }
}

extern "C" void kernel_launch(void* const* d_in, const int* in_sizes, int n_in,
                              void* d_out, int out_size, void* d_ws, size_t ws_size,
                              hipStream_t stream) {
  const float* x  = (const float*)d_in[0];
  const float* Wq = (const float*)d_in[1];
  const float* Wk = (const float*)d_in[2];
  const float* Wv = (const float*)d_in[3];
  const float* rf = (const float*)d_in[4];
  const float* Wo = (const float*)d_in[5];
  const float* bo = (const float*)d_in[6];
  float* out = (float*)d_out;
  float* ws = (float*)d_ws;

  float* q     = ws + OFF_Q;
  float* k     = ws + OFF_K;
  float* v     = ws + OFF_V;
  float* rft   = ws + OFF_RFT;
  float* kvp   = ws + OFF_KVP;
  float* ksump = ws + OFF_KSUMP;
  float* kvt   = ws + OFF_KVT;
  float* ksum  = ws + OFF_KSUM;
  float* attn  = k;  // k is dead after kv_partial; reuse for attn

  rft_kernel<<<64, 256, 0, stream>>>(rf, rft);
  gemm512<false><<<512, 256, 0, stream>>>(x, Wq, nullptr, q);
  gemm512<false><<<512, 256, 0, stream>>>(x, Wk, nullptr, k);
  gemm512<false><<<512, 256, 0, stream>>>(x, Wv, nullptr, v);
  kv_partial<<<B * H * NCH, 256, 0, stream>>>(k, v, rft, kvp, ksump);
  kv_reduce<<<2048, 256, 0, stream>>>(kvp, ksump, kvt, ksum);
  attn_num<<<512, 256, 0, stream>>>(q, rft, kvt, ksum, attn);
  gemm512<true><<<512, 256, 0, stream>>>(attn, Wo, bo, out);
}

// Round 2
// 905.926 us; speedup vs baseline: 1.3047x; 1.3047x over previous
//
#include <hip/hip_runtime.h>
#include <hip/hip_bf16.h>
#include <cstdint>

// Performer (FAVOR+) non-causal attention. B=4 S=4096 D=512 H=8 KD=64 R=256.
// Round 1: four 512-K GEMMs -> split-bf16 (hi/lo) 3-pass MFMA GEMMs.
constexpr int B = 4, S = 4096, D = 512, H = 8, KD = 64, R = 256;
constexpr int M = B * S;          // 16384 rows
constexpr float EPS = 1e-3f;
constexpr int NCH = 16;           // S-chunks for kv partial accumulation
constexpr int CHS = S / NCH;      // 256

typedef unsigned short u16;
typedef __attribute__((ext_vector_type(8))) short bf16x8;
typedef __attribute__((ext_vector_type(4))) float f32x4;

// ws layout (float offsets) — identical footprint to the proven round-0 layout.
constexpr size_t OFF_Q     = 0;          // q fp32; later attn hi/lo (bf16)
constexpr size_t OFF_K     = 8388608;    // k fp32; later attn fp32
constexpr size_t OFF_V     = 16777216;   // v fp32
constexpr size_t OFF_RFT   = 25165824;   // rf^T * SCALE, [d][r] fp32
constexpr size_t OFF_KVP   = 25182208;   // Wq/Wk/Wv hi/lo splits (3MB), then kvp
constexpr size_t OFF_KSUMP = 33570816;
constexpr size_t OFF_KVT   = 33701888;   // kvt; later Wo hi/lo split
constexpr size_t OFF_KSUM  = 34226176;
// total 136,937,472 B. x hi/lo splits live in d_out (dead until final GEMM).

__device__ __forceinline__ float bcast(float x, int lane) {
  return __int_as_float(__builtin_amdgcn_readlane(__float_as_int(x), lane));
}
__device__ __forceinline__ u16 f2bf(float f) {
  unsigned u = __float_as_uint(f);
  return (u16)((u + 0x7FFF + ((u >> 16) & 1)) >> 16);  // RNE
}
__device__ __forceinline__ float bf2f(u16 b) {
  return __uint_as_float(((unsigned)b) << 16);
}
__device__ __forceinline__ void gl_lds16(const void* g, void* l) {
  __builtin_amdgcn_global_load_lds(
      (const __attribute__((address_space(1))) unsigned int*)g,
      (__attribute__((address_space(3))) unsigned int*)l, 16, 0, 0);
}

// split fp32 -> bf16 hi + bf16 lo (residual), vectorized x4
__global__ __launch_bounds__(256) void split_kernel(const float* __restrict__ in,
                                                    u16* __restrict__ hi,
                                                    u16* __restrict__ lo, int n4) {
  int i = blockIdx.x * 256 + threadIdx.x;
  if (i >= n4) return;
  float4 v = ((const float4*)in)[i];
  u16 h0 = f2bf(v.x), h1 = f2bf(v.y), h2 = f2bf(v.z), h3 = f2bf(v.w);
  u16 l0 = f2bf(v.x - bf2f(h0)), l1 = f2bf(v.y - bf2f(h1));
  u16 l2 = f2bf(v.z - bf2f(h2)), l3 = f2bf(v.w - bf2f(h3));
  ((ushort4*)hi)[i] = make_ushort4(h0, h1, h2, h3);
  ((ushort4*)lo)[i] = make_ushort4(l0, l1, l2, l3);
}

// W[512k][512n] -> transposed splits Wt_hi/Wt_lo [n][k] bf16
__global__ __launch_bounds__(256) void splitT_kernel(const float* __restrict__ W,
                                                     u16* __restrict__ hi,
                                                     u16* __restrict__ lo) {
  int i = blockIdx.x * 256 + threadIdx.x;  // 262144 = [n][k]
  int n = i >> 9, k = i & 511;
  float v = W[(size_t)k * 512 + n];
  u16 h = f2bf(v);
  hi[i] = h;
  lo[i] = f2bf(v - bf2f(h));
}

// rft[d*256 + r] = rf[r*64 + d] * SCALE
__global__ __launch_bounds__(256) void rft_kernel(const float* __restrict__ rf,
                                                  float* __restrict__ rft) {
  int i = blockIdx.x * 256 + threadIdx.x;  // 16384
  int dd = i >> 8, rr = i & 255;
  rft[i] = rf[rr * KD + dd] * 0.125f;
}

// C[M x 512] = (Ah+Al)[M x 512] @ (Wh+Wl)^T(+bias), 3-pass split-bf16 MFMA.
// A: [m][k] bf16 row-major. Wt: [n][k] bf16 row-major. 128x128 tile, BK=32,
// 4 waves each computing 64x64 (4x4 frags of 16x16x32).
// LDS tiles [128][32] bf16 with XOR slot swizzle: 16B slot p of row r holds
// logical slot p ^ ((r>>1)&3) (2-way banks = free; staged via pre-swizzled
// global source so global_load_lds's linear dest stays consistent).
template <bool BIAS>
__global__ __launch_bounds__(256) void gemm_bf16(const u16* __restrict__ Ah,
                                                 const u16* __restrict__ Al,
                                                 const u16* __restrict__ Bh,
                                                 const u16* __restrict__ Bl,
                                                 const float* __restrict__ bias,
                                                 float* __restrict__ C) {
  __shared__ alignas(16) u16 lds[4][4096];  // Ah,Al,Bh,Bl tiles; 8KB each
  const int t = threadIdx.x, lane = t & 63, w = t >> 6;
  const int bm = (int)(blockIdx.x >> 2) * 128;
  const int bn = (int)(blockIdx.x & 3) * 128;
  const int wr = w >> 1, wc = w & 1;
  // staging lane constants: lane i -> row (i>>2) of 16-row group, phys slot i&3,
  // which must hold logical slot (i&3) ^ swz(row), swz(row)=(row>>1)&3=(i>>3)&3
  const int srow = lane >> 2;
  const int scol = (((lane & 3) ^ ((lane >> 3) & 3)) << 3);  // element col in tile
  // frag-read lane constants: row fm=lane&15, k-group fg=lane>>4,
  // byte off within 16-row frag block = fm*64 + ((fg^((fm>>1)&3))<<4)
  const int fm = lane & 15, fg = lane >> 4;
  const int foff = fm * 64 + (((fg ^ ((fm >> 1) & 3)) & 3) << 4);
  f32x4 acc[4][4];
#pragma unroll
  for (int i = 0; i < 4; ++i)
#pragma unroll
    for (int j = 0; j < 4; ++j) acc[i][j] = {0.f, 0.f, 0.f, 0.f};

  const int rg = w * 32;  // this wave stages rows [rg, rg+32) of each tile
  for (int k0 = 0; k0 < 512; k0 += 32) {
    __syncthreads();  // prev iteration's ds_reads done before overwrite
#pragma unroll
    for (int L = 0; L < 2; ++L) {
      const int rloc = rg + L * 16;
      const size_t ga = (((size_t)(bm + rloc + srow)) << 9) + (size_t)(k0 + scol);
      const size_t gb = (((size_t)(bn + rloc + srow)) << 9) + (size_t)(k0 + scol);
      char* ldst = (char*)lds + rloc * 64;
      gl_lds16(Ah + ga, ldst);
      gl_lds16(Al + ga, ldst + 8192);
      gl_lds16(Bh + gb, ldst + 16384);
      gl_lds16(Bl + gb, ldst + 24576);
    }
    __syncthreads();  // vmcnt(0) drained by compiler before barrier
    bf16x8 ah[4], al[4], bh[4], bl[4];
#pragma unroll
    for (int i = 0; i < 4; ++i) {
      const int ro = (wr * 64 + 16 * i) * 64 + foff;
      const int co = (wc * 64 + 16 * i) * 64 + foff;
      ah[i] = *(const bf16x8*)((const char*)lds + ro);
      al[i] = *(const bf16x8*)((const char*)lds + 8192 + ro);
      bh[i] = *(const bf16x8*)((const char*)lds + 16384 + co);
      bl[i] = *(const bf16x8*)((const char*)lds + 24576 + co);
    }
#pragma unroll
    for (int i = 0; i < 4; ++i)
#pragma unroll
      for (int j = 0; j < 4; ++j) {
        acc[i][j] = __builtin_amdgcn_mfma_f32_16x16x32_bf16(ah[i], bh[j], acc[i][j], 0, 0, 0);
        acc[i][j] = __builtin_amdgcn_mfma_f32_16x16x32_bf16(ah[i], bl[j], acc[i][j], 0, 0, 0);
        acc[i][j] = __builtin_amdgcn_mfma_f32_16x16x32_bf16(al[i], bh[j], acc[i][j], 0, 0, 0);
      }
  }
  // C/D layout: n = lane&15, m = (lane>>4)*4 + reg  [guide-verified]
  const int cn = bn + wc * 64 + fm;
  const int rm0 = bm + wr * 64 + fg * 4;
#pragma unroll
  for (int j = 0; j < 4; ++j) {
    const float bv = BIAS ? bias[cn + 16 * j] : 0.f;
#pragma unroll
    for (int i = 0; i < 4; ++i)
#pragma unroll
      for (int r = 0; r < 4; ++r)
        C[(size_t)(rm0 + 16 * i + r) * 512 + cn + 16 * j] = acc[i][j][r] + bv;
  }
}

// Per (b,h,chunk): kvp[r][d] = sum_s kf(s,r)*v(s,d); ksump[r] = sum_s kf(s,r).
__global__ __launch_bounds__(256) void kv_partial(const float* __restrict__ kbuf,
                                                  const float* __restrict__ vbuf,
                                                  const float* __restrict__ rft,
                                                  float* __restrict__ kvp,
                                                  float* __restrict__ ksump) {
  __shared__ alignas(16) float rowbuf[2][128];
  __shared__ float maxbuf[2][4];
  const int t = threadIdx.x;       // t == r
  const int bid = blockIdx.x;      // B*H*NCH
  const int ch = bid & (NCH - 1);
  const int bh = bid / NCH;
  const int b = bh >> 3, h = bh & 7;
  const int lane = t & 63, w = t >> 6;
  float rfreg[64];
#pragma unroll
  for (int d = 0; d < 64; ++d) rfreg[d] = rft[d * 256 + t];
  float acc[64] = {};
  float ksacc = 0.f;
  const size_t base = (size_t)(b * S + ch * CHS) * 512 + h * 64;
  const float* krow = kbuf + base;
  const float* vrow = vbuf + base;
  for (int s = 0; s < CHS; ++s) {
    const int sl = s & 1;
    if (t < 128) {
      rowbuf[sl][t] = (t < 64) ? krow[(size_t)s * 512 + t]
                               : vrow[(size_t)s * 512 + (t - 64)];
    }
    __syncthreads();
    float proj = 0.f;
#pragma unroll
    for (int d4 = 0; d4 < 16; ++d4) {
      float4 kk = *(const float4*)&rowbuf[sl][d4 * 4];
      proj = fmaf(kk.x, rfreg[d4 * 4 + 0], proj);
      proj = fmaf(kk.y, rfreg[d4 * 4 + 1], proj);
      proj = fmaf(kk.z, rfreg[d4 * 4 + 2], proj);
      proj = fmaf(kk.w, rfreg[d4 * 4 + 3], proj);
    }
    float m2 = proj;
#pragma unroll
    for (int off = 32; off > 0; off >>= 1) m2 = fmaxf(m2, __shfl_xor(m2, off));
    if (lane == 0) maxbuf[sl][w] = m2;
    __syncthreads();
    float mm = fmaxf(fmaxf(maxbuf[sl][0], maxbuf[sl][1]),
                     fmaxf(maxbuf[sl][2], maxbuf[sl][3]));
    float kf = __expf(proj - mm) + EPS;
    ksacc += kf;
#pragma unroll
    for (int d4 = 0; d4 < 16; ++d4) {
      float4 vv = *(const float4*)&rowbuf[sl][64 + d4 * 4];
      acc[d4 * 4 + 0] = fmaf(kf, vv.x, acc[d4 * 4 + 0]);
      acc[d4 * 4 + 1] = fmaf(kf, vv.y, acc[d4 * 4 + 1]);
      acc[d4 * 4 + 2] = fmaf(kf, vv.z, acc[d4 * 4 + 2]);
      acc[d4 * 4 + 3] = fmaf(kf, vv.w, acc[d4 * 4 + 3]);
    }
  }
  float4* o = (float4*)&kvp[((size_t)bid * R + t) * KD];
#pragma unroll
  for (int d4 = 0; d4 < 16; ++d4)
    o[d4] = make_float4(acc[4 * d4], acc[4 * d4 + 1], acc[4 * d4 + 2], acc[4 * d4 + 3]);
  ksump[(size_t)bid * R + t] = ksacc;
}

__global__ __launch_bounds__(256) void kv_reduce(const float* __restrict__ kvp,
                                                 const float* __restrict__ ksump,
                                                 float* __restrict__ kvt,
                                                 float* __restrict__ ksum) {
  const int i = blockIdx.x * 256 + threadIdx.x;  // 524288
  const int bh = i >> 14;
  const int rd = i & 16383;
  const int r = rd >> 6, dd = rd & 63;
  float s = 0.f;
#pragma unroll
  for (int c = 0; c < NCH; ++c) s += kvp[(((size_t)(bh * NCH + c)) << 14) + rd];
  kvt[((size_t)bh << 14) + (size_t)(r >> 2) * 256 + dd * 4 + (r & 3)] = s;
  if (i < B * H * R) {
    const int bh2 = i >> 8, r2 = i & 255;
    float ss = 0.f;
#pragma unroll
    for (int c = 0; c < NCH; ++c) ss += ksump[(size_t)(bh2 * NCH + c) * R + r2];
    ksum[i] = ss;
  }
}

__global__ __launch_bounds__(256) void attn_num(const float* __restrict__ q,
                                                const float* __restrict__ rft,
                                                const float* __restrict__ kvt,
                                                const float* __restrict__ ksum,
                                                float* __restrict__ attn) {
  __shared__ alignas(16) float kvl[R * KD];  // 64KB
  __shared__ alignas(16) float ksl[R];
  const int t = threadIdx.x, lane = t & 63, w = t >> 6;
  const int bid = blockIdx.x;               // 512
  const int bh = bid >> 4, ch = bid & 15;
  const int b = bh >> 3, h = bh & 7;
  const float* kvsrc = kvt + ((size_t)bh << 14);
#pragma unroll
  for (int it = 0; it < 16; ++it) {
    int i = t * 4 + it * 1024;
    *(float4*)&kvl[i] = *(const float4*)&kvsrc[i];
  }
  ksl[t] = ksum[bh * R + t];
  __syncthreads();
  float ks4[4];
  {
    float4 kk = *(const float4*)&ksl[lane * 4];
    ks4[0] = kk.x; ks4[1] = kk.y; ks4[2] = kk.z; ks4[3] = kk.w;
  }
  const int sbase = ch * 256 + w * 64;
  for (int g = 0; g < 16; ++g) {
    const int s = sbase + g * 4;
    const float* qbase = q + (size_t)(b * S + s) * 512 + h * 64 + lane;
    float qv[4];
#pragma unroll
    for (int ts = 0; ts < 4; ++ts) qv[ts] = qbase[(size_t)ts * 512];
    float pj[4][4] = {};
#pragma unroll
    for (int d = 0; d < 64; ++d) {
      float4 rfv = *(const float4*)&rft[d * 256 + lane * 4];
#pragma unroll
      for (int ts = 0; ts < 4; ++ts) {
        float qd = bcast(qv[ts], d);
        pj[ts][0] = fmaf(qd, rfv.x, pj[ts][0]);
        pj[ts][1] = fmaf(qd, rfv.y, pj[ts][1]);
        pj[ts][2] = fmaf(qd, rfv.z, pj[ts][2]);
        pj[ts][3] = fmaf(qd, rfv.w, pj[ts][3]);
      }
    }
    float qf[4][4], rden[4];
#pragma unroll
    for (int ts = 0; ts < 4; ++ts) {
      float m2 = fmaxf(fmaxf(pj[ts][0], pj[ts][1]), fmaxf(pj[ts][2], pj[ts][3]));
#pragma unroll
      for (int off = 32; off > 0; off >>= 1) m2 = fmaxf(m2, __shfl_xor(m2, off));
      float dacc = 0.f;
#pragma unroll
      for (int i = 0; i < 4; ++i) {
        qf[ts][i] = __expf(pj[ts][i] - m2) + EPS;
        dacc = fmaf(qf[ts][i], ks4[i], dacc);
      }
#pragma unroll
      for (int off = 32; off > 0; off >>= 1) dacc += __shfl_xor(dacc, off);
      rden[ts] = 1.0f / (dacc + EPS);
    }
    float num[4] = {0.f, 0.f, 0.f, 0.f};
#pragma unroll 8
    for (int r4 = 0; r4 < 64; ++r4) {
      float4 kvv = *(const float4*)&kvl[r4 * 256 + lane * 4];
#pragma unroll
      for (int ts = 0; ts < 4; ++ts) {
        num[ts] = fmaf(bcast(qf[ts][0], r4), kvv.x, num[ts]);
        num[ts] = fmaf(bcast(qf[ts][1], r4), kvv.y, num[ts]);
        num[ts] = fmaf(bcast(qf[ts][2], r4), kvv.z, num[ts]);
        num[ts] = fmaf(bcast(qf[ts][3], r4), kvv.w, num[ts]);
      }
    }
    float* obase = attn + (size_t)(b * S + s) * 512 + h * 64 + lane;
#pragma unroll
    for (int ts = 0; ts < 4; ++ts) obase[(size_t)ts * 512] = num[ts] * rden[ts];
  }
}

extern "C" void kernel_launch(void* const* d_in, const int* in_sizes, int n_in,
                              void* d_out, int out_size, void* d_ws, size_t ws_size,
                              hipStream_t stream) {
  const float* x  = (const float*)d_in[0];
  const float* Wq = (const float*)d_in[1];
  const float* Wk = (const float*)d_in[2];
  const float* Wv = (const float*)d_in[3];
  const float* rf = (const float*)d_in[4];
  const float* Wo = (const float*)d_in[5];
  const float* bo = (const float*)d_in[6];
  float* out = (float*)d_out;
  float* ws = (float*)d_ws;

  float* q     = ws + OFF_Q;
  float* k     = ws + OFF_K;
  float* v     = ws + OFF_V;
  float* rft   = ws + OFF_RFT;
  float* kvp   = ws + OFF_KVP;
  float* ksump = ws + OFF_KSUMP;
  float* kvt   = ws + OFF_KVT;
  float* ksum  = ws + OFF_KSUM;
  float* attn  = k;                      // k dead after kv_partial

  // bf16 scratch, time-multiplexed into dead regions:
  u16* xh   = (u16*)d_out;               // d_out dead until final GEMM
  u16* xl   = xh + 8388608;
  u16* wt   = (u16*)(ws + OFF_KVP);      // kvp region dead until kv_partial
  u16* wtq_h = wt,            *wtq_l = wt + 262144;
  u16* wtk_h = wt + 524288,   *wtk_l = wt + 786432;
  u16* wtv_h = wt + 1048576,  *wtv_l = wt + 1310720;
  u16* wto_h = (u16*)(ws + OFF_KVT);     // kvt dead after attn_num
  u16* wto_l = wto_h + 262144;
  u16* attnh = (u16*)(ws + OFF_Q);       // q dead after attn_num
  u16* attnl = attnh + 8388608;

  split_kernel<<<8192, 256, 0, stream>>>(x, xh, xl, 2097152);
  splitT_kernel<<<1024, 256, 0, stream>>>(Wq, wtq_h, wtq_l);
  splitT_kernel<<<1024, 256, 0, stream>>>(Wk, wtk_h, wtk_l);
  splitT_kernel<<<1024, 256, 0, stream>>>(Wv, wtv_h, wtv_l);
  rft_kernel<<<64, 256, 0, stream>>>(rf, rft);
  gemm_bf16<false><<<512, 256, 0, stream>>>(xh, xl, wtq_h, wtq_l, nullptr, q);
  gemm_bf16<false><<<512, 256, 0, stream>>>(xh, xl, wtk_h, wtk_l, nullptr, k);
  gemm_bf16<false><<<512, 256, 0, stream>>>(xh, xl, wtv_h, wtv_l, nullptr, v);
  kv_partial<<<B * H * NCH, 256, 0, stream>>>(k, v, rft, kvp, ksump);
  kv_reduce<<<2048, 256, 0, stream>>>(kvp, ksump, kvt, ksum);
  attn_num<<<512, 256, 0, stream>>>(q, rft, kvt, ksum, attn);
  splitT_kernel<<<1024, 256, 0, stream>>>(Wo, wto_h, wto_l);
  split_kernel<<<8192, 256, 0, stream>>>(attn, attnh, attnl, 2097152);
  gemm_bf16<true><<<512, 256, 0, stream>>>(attnh, attnl, wto_h, wto_l, bo, out);
}

// Round 4
// 606.340 us; speedup vs baseline: 1.9493x; 1.4941x over previous
//
#include <hip/hip_runtime.h>
#include <hip/hip_bf16.h>
#include <cstdint>

// Performer (FAVOR+) non-causal attention. B=4 S=4096 D=512 H=8 KD=64 R=256.
// R2/R3: attn_num -> MFMA (qproj feature kernel + num GEMM), q/qf/kv as bf16 images.
constexpr int B = 4, S = 4096, D = 512, H = 8, KD = 64, R = 256;
constexpr int M = B * S;          // 16384 rows
constexpr float EPS = 1e-3f;
constexpr int NCH = 16;
constexpr int CHS = S / NCH;      // 256

typedef unsigned short u16;
typedef __attribute__((ext_vector_type(8))) short bf16x8;
typedef __attribute__((ext_vector_type(4))) float f32x4;

// ws layout (float offsets); peak = 34234368 floats = 136.94 MB (as round 0/1)
constexpr size_t OFF_Q     = 0;          // qim bf16 (16.8MB); later attnh/attnl
constexpr size_t OFF_K     = 8388608;    // k fp32; later attn fp32
constexpr size_t OFF_V     = 16777216;   // v fp32; later qf chunk0; later Wo splits
constexpr size_t OFF_RFT   = 25165824;   // rft fp32 [d][r] (16384)
constexpr size_t OFF_KVP   = 25182208;   // W splits; kvp; later qf chunk1
constexpr size_t OFF_KSUMP = 33570816;   // 131072
constexpr size_t OFF_KVIM  = 33701888;   // kv bf16 image (262144 float-slots)
constexpr size_t OFF_RDEN  = 33964032;   // rden fp32 (131072)
constexpr size_t OFF_RFIM  = 34095104;   // rf bf16 B-image (8192 float-slots)
constexpr size_t OFF_KSUM  = 34226176;   // 8192

__device__ __forceinline__ u16 f2bf(float f) {
  unsigned u = __float_as_uint(f);
  return (u16)((u + 0x7FFF + ((u >> 16) & 1)) >> 16);  // RNE
}
__device__ __forceinline__ float bf2f(u16 b) {
  return __uint_as_float(((unsigned)b) << 16);
}
__device__ __forceinline__ void gl_lds16(const void* g, void* l) {
  __builtin_amdgcn_global_load_lds(
      (const __attribute__((address_space(1))) unsigned int*)g,
      (__attribute__((address_space(3))) unsigned int*)l, 16, 0, 0);
}
__device__ __forceinline__ f32x4 mfma16(bf16x8 a, bf16x8 b, f32x4 c) {
  return __builtin_amdgcn_mfma_f32_16x16x32_bf16(a, b, c, 0, 0, 0);
}

// ---------- preprocessing ----------
__global__ __launch_bounds__(256) void split_kernel(const float* __restrict__ in,
                                                    u16* __restrict__ hi,
                                                    u16* __restrict__ lo, int n4) {
  int i = blockIdx.x * 256 + threadIdx.x;
  if (i >= n4) return;
  float4 v = ((const float4*)in)[i];
  u16 h0 = f2bf(v.x), h1 = f2bf(v.y), h2 = f2bf(v.z), h3 = f2bf(v.w);
  u16 l0 = f2bf(v.x - bf2f(h0)), l1 = f2bf(v.y - bf2f(h1));
  u16 l2 = f2bf(v.z - bf2f(h2)), l3 = f2bf(v.w - bf2f(h3));
  ((ushort4*)hi)[i] = make_ushort4(h0, h1, h2, h3);
  ((ushort4*)lo)[i] = make_ushort4(l0, l1, l2, l3);
}

__global__ __launch_bounds__(256) void splitT_kernel(const float* __restrict__ W,
                                                     u16* __restrict__ hi,
                                                     u16* __restrict__ lo) {
  int i = blockIdx.x * 256 + threadIdx.x;  // [n][k]
  int n = i >> 9, k = i & 511;
  float v = W[(size_t)k * 512 + n];
  u16 h = f2bf(v);
  hi[i] = h;
  lo[i] = f2bf(v - bf2f(h));
}

// rft fp32 [d][r] (for kv_partial) + rfim bf16 B-image [r][64 k] slot-swizzled
__global__ __launch_bounds__(256) void rft_kernel(const float* __restrict__ rf,
                                                  float* __restrict__ rft,
                                                  u16* __restrict__ rfim) {
  int i = blockIdx.x * 256 + threadIdx.x;  // 16384
  int dd = i >> 8, rr = i & 255;
  rft[i] = rf[rr * KD + dd] * 0.125f;
  int r2 = i >> 6, d2 = i & 63;
  float v = rf[r2 * KD + d2] * 0.125f;
  rfim[r2 * 64 + (((d2 >> 3) ^ (r2 & 7)) << 3) + (d2 & 7)] = f2bf(v);
}

// ---------- split-bf16 3-pass GEMM (128x128 tile), three output modes ----------
// OMODE 0: fp32, no bias. 1: fp32 + bias. 2: q bf16 image (per-bh, swizzled).
template <int OMODE>
__global__ __launch_bounds__(256) void gemm_bf16(const u16* __restrict__ Ah,
                                                 const u16* __restrict__ Al,
                                                 const u16* __restrict__ Bh,
                                                 const u16* __restrict__ Bl,
                                                 const float* __restrict__ bias,
                                                 float* __restrict__ C,
                                                 u16* __restrict__ Cimg) {
  __shared__ alignas(16) u16 lds[4][4096];
  const int t = threadIdx.x, lane = t & 63, w = t >> 6;
  const int bm = (int)(blockIdx.x >> 2) * 128;
  const int bn = (int)(blockIdx.x & 3) * 128;
  const int wr = w >> 1, wc = w & 1;
  const int srow = lane >> 2;
  const int scol = (((lane & 3) ^ ((lane >> 3) & 3)) << 3);
  const int fm = lane & 15, fg = lane >> 4;
  const int foff = fm * 64 + (((fg ^ ((fm >> 1) & 3)) & 3) << 4);
  f32x4 acc[4][4];
#pragma unroll
  for (int i = 0; i < 4; ++i)
#pragma unroll
    for (int j = 0; j < 4; ++j) acc[i][j] = {0.f, 0.f, 0.f, 0.f};

  const int rg = w * 32;
  for (int k0 = 0; k0 < 512; k0 += 32) {
    __syncthreads();
#pragma unroll
    for (int L = 0; L < 2; ++L) {
      const int rloc = rg + L * 16;
      const size_t ga = (((size_t)(bm + rloc + srow)) << 9) + (size_t)(k0 + scol);
      const size_t gb = (((size_t)(bn + rloc + srow)) << 9) + (size_t)(k0 + scol);
      char* ldst = (char*)lds + rloc * 64;
      gl_lds16(Ah + ga, ldst);
      gl_lds16(Al + ga, ldst + 8192);
      gl_lds16(Bh + gb, ldst + 16384);
      gl_lds16(Bl + gb, ldst + 24576);
    }
    __syncthreads();
    bf16x8 ah[4], al[4], bh[4], bl[4];
#pragma unroll
    for (int i = 0; i < 4; ++i) {
      const int ro = (wr * 64 + 16 * i) * 64 + foff;
      const int co = (wc * 64 + 16 * i) * 64 + foff;
      ah[i] = *(const bf16x8*)((const char*)lds + ro);
      al[i] = *(const bf16x8*)((const char*)lds + 8192 + ro);
      bh[i] = *(const bf16x8*)((const char*)lds + 16384 + co);
      bl[i] = *(const bf16x8*)((const char*)lds + 24576 + co);
    }
#pragma unroll
    for (int i = 0; i < 4; ++i)
#pragma unroll
      for (int j = 0; j < 4; ++j) {
        acc[i][j] = mfma16(ah[i], bh[j], acc[i][j]);
        acc[i][j] = mfma16(ah[i], bl[j], acc[i][j]);
        acc[i][j] = mfma16(al[i], bh[j], acc[i][j]);
      }
  }
  const int cn = bn + wc * 64 + fm;
  const int rm0 = bm + wr * 64 + fg * 4;
#pragma unroll
  for (int j = 0; j < 4; ++j) {
#pragma unroll
    for (int i = 0; i < 4; ++i)
#pragma unroll
      for (int r = 0; r < 4; ++r) {
        const int mg = rm0 + 16 * i + r;
        const int n = cn + 16 * j;
        if (OMODE == 2) {
          const int bh_ = (mg >> 12) * 8 + (n >> 6);
          const int sl = mg & 4095, d = n & 63;
          Cimg[(size_t)bh_ * 262144 + sl * 64 + (((d >> 3) ^ (sl & 7)) << 3) + (d & 7)] =
              f2bf(acc[i][j][r]);
        } else {
          float o = acc[i][j][r] + (OMODE == 1 ? bias[n] : 0.f);
          C[(size_t)mg * 512 + n] = o;
        }
      }
  }
}

// ---------- kv over s (unchanged VALU version this round) ----------
__global__ __launch_bounds__(256) void kv_partial(const float* __restrict__ kbuf,
                                                  const float* __restrict__ vbuf,
                                                  const float* __restrict__ rft,
                                                  float* __restrict__ kvp,
                                                  float* __restrict__ ksump) {
  __shared__ alignas(16) float rowbuf[2][128];
  __shared__ float maxbuf[2][4];
  const int t = threadIdx.x;
  const int bid = blockIdx.x;
  const int ch = bid & (NCH - 1);
  const int bh = bid / NCH;
  const int b = bh >> 3, h = bh & 7;
  const int lane = t & 63, w = t >> 6;
  float rfreg[64];
#pragma unroll
  for (int d = 0; d < 64; ++d) rfreg[d] = rft[d * 256 + t];
  float acc[64] = {};
  float ksacc = 0.f;
  const size_t base = (size_t)(b * S + ch * CHS) * 512 + h * 64;
  const float* krow = kbuf + base;
  const float* vrow = vbuf + base;
  for (int s = 0; s < CHS; ++s) {
    const int sl = s & 1;
    if (t < 128) {
      rowbuf[sl][t] = (t < 64) ? krow[(size_t)s * 512 + t]
                               : vrow[(size_t)s * 512 + (t - 64)];
    }
    __syncthreads();
    float proj = 0.f;
#pragma unroll
    for (int d4 = 0; d4 < 16; ++d4) {
      float4 kk = *(const float4*)&rowbuf[sl][d4 * 4];
      proj = fmaf(kk.x, rfreg[d4 * 4 + 0], proj);
      proj = fmaf(kk.y, rfreg[d4 * 4 + 1], proj);
      proj = fmaf(kk.z, rfreg[d4 * 4 + 2], proj);
      proj = fmaf(kk.w, rfreg[d4 * 4 + 3], proj);
    }
    float m2 = proj;
#pragma unroll
    for (int off = 32; off > 0; off >>= 1) m2 = fmaxf(m2, __shfl_xor(m2, off));
    if (lane == 0) maxbuf[sl][w] = m2;
    __syncthreads();
    float mm = fmaxf(fmaxf(maxbuf[sl][0], maxbuf[sl][1]),
                     fmaxf(maxbuf[sl][2], maxbuf[sl][3]));
    float kf = __expf(proj - mm) + EPS;
    ksacc += kf;
#pragma unroll
    for (int d4 = 0; d4 < 16; ++d4) {
      float4 vv = *(const float4*)&rowbuf[sl][64 + d4 * 4];
      acc[d4 * 4 + 0] = fmaf(kf, vv.x, acc[d4 * 4 + 0]);
      acc[d4 * 4 + 1] = fmaf(kf, vv.y, acc[d4 * 4 + 1]);
      acc[d4 * 4 + 2] = fmaf(kf, vv.z, acc[d4 * 4 + 2]);
      acc[d4 * 4 + 3] = fmaf(kf, vv.w, acc[d4 * 4 + 3]);
    }
  }
  float4* o = (float4*)&kvp[((size_t)bid * R + t) * KD];
#pragma unroll
  for (int d4 = 0; d4 < 16; ++d4)
    o[d4] = make_float4(acc[4 * d4], acc[4 * d4 + 1], acc[4 * d4 + 2], acc[4 * d4 + 3]);
  ksump[(size_t)bid * R + t] = ksacc;
}

// reduce partials -> kv bf16 B-image [bh][d-row 512B][r slots swizzled] + ksum fp32
__global__ __launch_bounds__(256) void kv_reduce(const float* __restrict__ kvp,
                                                 const float* __restrict__ ksump,
                                                 u16* __restrict__ kvim,
                                                 float* __restrict__ ksum) {
  const int i = blockIdx.x * 256 + threadIdx.x;  // 524288
  const int bh = i >> 14;
  const int rd = i & 16383;
  const int r = rd >> 6, dd = rd & 63;
  float s = 0.f;
#pragma unroll
  for (int c = 0; c < NCH; ++c) s += kvp[(((size_t)(bh * NCH + c)) << 14) + rd];
  kvim[(size_t)bh * 16384 + dd * 256 + (((r >> 3) ^ (dd & 7)) << 3) + (r & 7)] = f2bf(s);
  if (i < B * H * R) {
    const int bh2 = i >> 8, r2 = i & 255;
    float ss = 0.f;
#pragma unroll
    for (int c = 0; c < NCH; ++c) ss += ksump[(size_t)(bh2 * NCH + c) * R + r2];
    ksum[i] = ss;
  }
}

// ---------- qf features: proj MFMA + max/exp/den, writes qf bf16 A-image ----------
// grid: 32 bh * 32 s-tiles(128). 4 waves * 32 s each.
__global__ __launch_bounds__(256) void qproj_kernel(const u16* __restrict__ qim,
                                                    const u16* __restrict__ rfim,
                                                    const float* __restrict__ ksum,
                                                    u16* __restrict__ qf0,
                                                    u16* __restrict__ qf1,
                                                    float* __restrict__ rden) {
  __shared__ alignas(16) u16 lds_rf[16384];  // [256][64] image, 32KB
  __shared__ alignas(16) u16 lds_q[8192];    // [128][64] image, 16KB
  const int t = threadIdx.x, lane = t & 63, w = t >> 6;
  const int bid = blockIdx.x;
  const int bh = bid >> 5, stile = bid & 31;
  const int fm = lane & 15, fg = lane >> 4;
  u16* qf = (bh < 16 ? qf0 : qf1) + (size_t)(bh & 15) * 1048576;
  const u16* qsrc = qim + (size_t)bh * 262144 + (size_t)stile * 8192;
#pragma unroll
  for (int rnd = 0; rnd < 8; ++rnd)
    gl_lds16(rfim + rnd * 2048 + w * 512 + lane * 8,
             (char*)lds_rf + rnd * 4096 + w * 1024 + lane * 16);
#pragma unroll
  for (int rnd = 0; rnd < 4; ++rnd)
    gl_lds16(qsrc + rnd * 2048 + w * 512 + lane * 8,
             (char*)lds_q + rnd * 4096 + w * 1024 + lane * 16);
  __syncthreads();
  f32x4 acc[2][16];
#pragma unroll
  for (int i = 0; i < 2; ++i)
#pragma unroll
    for (int j = 0; j < 16; ++j) acc[i][j] = {0.f, 0.f, 0.f, 0.f};
#pragma unroll
  for (int c = 0; c < 2; ++c) {
    const int so = (((c * 4 + fg) ^ (fm & 7)) << 4);
    bf16x8 a[2];
#pragma unroll
    for (int i = 0; i < 2; ++i)
      a[i] = *(const bf16x8*)((const char*)lds_q + (w * 32 + 16 * i + fm) * 128 + so);
#pragma unroll
    for (int j = 0; j < 16; ++j) {
      bf16x8 b = *(const bf16x8*)((const char*)lds_rf + (16 * j + fm) * 128 + so);
      acc[0][j] = mfma16(a[0], b, acc[0][j]);
      acc[1][j] = mfma16(a[1], b, acc[1][j]);
    }
  }
  float ksl[16];
#pragma unroll
  for (int j = 0; j < 16; ++j) ksl[j] = ksum[bh * 256 + 16 * j + fm];
#pragma unroll
  for (int i = 0; i < 2; ++i) {
    float m2[4] = {-1e30f, -1e30f, -1e30f, -1e30f};
#pragma unroll
    for (int j = 0; j < 16; ++j)
#pragma unroll
      for (int r = 0; r < 4; ++r) m2[r] = fmaxf(m2[r], acc[i][j][r]);
#pragma unroll
    for (int r = 0; r < 4; ++r)
#pragma unroll
      for (int off = 1; off < 16; off <<= 1) m2[r] = fmaxf(m2[r], __shfl_xor(m2[r], off));
    float den[4] = {0.f, 0.f, 0.f, 0.f};
    const int s0 = stile * 128 + w * 32 + 16 * i + fg * 4;  // + r
#pragma unroll
    for (int j = 0; j < 16; ++j) {
      const int rr = fm + 16 * j;
#pragma unroll
      for (int r = 0; r < 4; ++r) {
        float e = __expf(acc[i][j][r] - m2[r]) + EPS;
        den[r] = fmaf(e, ksl[j], den[r]);
        const int s = s0 + r;
        qf[(size_t)s * 256 + (((rr >> 3) ^ (s & 7)) << 3) + (rr & 7)] = f2bf(e);
      }
    }
#pragma unroll
    for (int r = 0; r < 4; ++r) {
#pragma unroll
      for (int off = 1; off < 16; off <<= 1) den[r] += __shfl_xor(den[r], off);
      if (fm == 0) rden[bh * 4096 + s0 + r] = 1.0f / (den[r] + EPS);
    }
  }
}

// ---------- num GEMM: attn = (qf @ kv) * rden ----------
// grid: 32 bh * 64 s-tiles(64). 4 waves * 16 s each; N=64, K=256 fully staged.
__global__ __launch_bounds__(256) void num_gemm(const u16* __restrict__ qf0,
                                                const u16* __restrict__ qf1,
                                                const u16* __restrict__ kvim,
                                                const float* __restrict__ rden,
                                                float* __restrict__ attn) {
  __shared__ alignas(16) u16 lds_kv[16384];  // [64][256] image
  __shared__ alignas(16) u16 lds_qf[16384];  // [64][256] image
  const int t = threadIdx.x, lane = t & 63, w = t >> 6;
  const int bid = blockIdx.x;
  const int bh = bid >> 6, stile = bid & 63;
  const int fm = lane & 15, fg = lane >> 4;
  const u16* qf = (bh < 16 ? qf0 : qf1) + (size_t)(bh & 15) * 1048576 +
                  (size_t)stile * 16384;
  const u16* kvsrc = kvim + (size_t)bh * 16384;
#pragma unroll
  for (int rnd = 0; rnd < 8; ++rnd) {
    gl_lds16(kvsrc + rnd * 2048 + w * 512 + lane * 8,
             (char*)lds_kv + rnd * 4096 + w * 1024 + lane * 16);
    gl_lds16(qf + rnd * 2048 + w * 512 + lane * 8,
             (char*)lds_qf + rnd * 4096 + w * 1024 + lane * 16);
  }
  __syncthreads();
  f32x4 acc[4];
#pragma unroll
  for (int j = 0; j < 4; ++j) acc[j] = {0.f, 0.f, 0.f, 0.f};
#pragma unroll
  for (int c = 0; c < 8; ++c) {
    const int so = (((c * 4 + fg) ^ (fm & 7)) << 4);
    bf16x8 a = *(const bf16x8*)((const char*)lds_qf + (w * 16 + fm) * 512 + so);
#pragma unroll
    for (int j = 0; j < 4; ++j) {
      bf16x8 b = *(const bf16x8*)((const char*)lds_kv + (16 * j + fm) * 512 + so);
      acc[j] = mfma16(a, b, acc[j]);
    }
  }
  const int b = bh >> 3, h = bh & 7;
  const int s0 = stile * 64 + w * 16 + fg * 4;
  float rd4[4];
#pragma unroll
  for (int r = 0; r < 4; ++r) rd4[r] = rden[bh * 4096 + s0 + r];
#pragma unroll
  for (int j = 0; j < 4; ++j)
#pragma unroll
    for (int r = 0; r < 4; ++r)
      attn[(size_t)(b * 4096 + s0 + r) * 512 + h * 64 + fm + 16 * j] = acc[j][r] * rd4[r];
}

extern "C" void kernel_launch(void* const* d_in, const int* in_sizes, int n_in,
                              void* d_out, int out_size, void* d_ws, size_t ws_size,
                              hipStream_t stream) {
  const float* x  = (const float*)d_in[0];
  const float* Wq = (const float*)d_in[1];
  const float* Wk = (const float*)d_in[2];
  const float* Wv = (const float*)d_in[3];
  const float* rf = (const float*)d_in[4];
  const float* Wo = (const float*)d_in[5];
  const float* bo = (const float*)d_in[6];
  float* out = (float*)d_out;
  float* ws = (float*)d_ws;

  u16*   qim   = (u16*)(ws + OFF_Q);
  float* k     = ws + OFF_K;
  float* v     = ws + OFF_V;
  float* rft   = ws + OFF_RFT;
  float* kvp   = ws + OFF_KVP;
  float* ksump = ws + OFF_KSUMP;
  u16*   kvim  = (u16*)(ws + OFF_KVIM);
  float* rden  = ws + OFF_RDEN;
  u16*   rfim  = (u16*)(ws + OFF_RFIM);
  float* ksum  = ws + OFF_KSUM;
  float* attn  = k;                      // k dead after kv_partial

  u16* xh = (u16*)d_out;                 // d_out dead until final GEMM
  u16* xl = xh + 8388608;
  u16* wt = (u16*)(ws + OFF_KVP);        // dead before kv_partial writes kvp
  u16 *wtq_h = wt,           *wtq_l = wt + 262144;
  u16 *wtk_h = wt + 524288,  *wtk_l = wt + 786432;
  u16 *wtv_h = wt + 1048576, *wtv_l = wt + 1310720;
  u16* qf0 = (u16*)(ws + OFF_V);         // v dead after kv_partial
  u16* qf1 = (u16*)(ws + OFF_KVP);       // kvp dead after kv_reduce
  u16* wto_h = (u16*)(ws + OFF_V);       // qf0 dead after num_gemm
  u16* wto_l = wto_h + 262144;
  u16* attnh = (u16*)(ws + OFF_Q);       // qim dead after qproj
  u16* attnl = attnh + 8388608;

  split_kernel<<<8192, 256, 0, stream>>>(x, xh, xl, 2097152);
  splitT_kernel<<<1024, 256, 0, stream>>>(Wq, wtq_h, wtq_l);
  splitT_kernel<<<1024, 256, 0, stream>>>(Wk, wtk_h, wtk_l);
  splitT_kernel<<<1024, 256, 0, stream>>>(Wv, wtv_h, wtv_l);
  rft_kernel<<<64, 256, 0, stream>>>(rf, rft, rfim);
  gemm_bf16<0><<<512, 256, 0, stream>>>(xh, xl, wtk_h, wtk_l, nullptr, k, nullptr);
  gemm_bf16<0><<<512, 256, 0, stream>>>(xh, xl, wtv_h, wtv_l, nullptr, v, nullptr);
  gemm_bf16<2><<<512, 256, 0, stream>>>(xh, xl, wtq_h, wtq_l, nullptr, nullptr, qim);
  kv_partial<<<B * H * NCH, 256, 0, stream>>>(k, v, rft, kvp, ksump);
  kv_reduce<<<2048, 256, 0, stream>>>(kvp, ksump, kvim, ksum);
  qproj_kernel<<<1024, 256, 0, stream>>>(qim, rfim, ksum, qf0, qf1, rden);
  num_gemm<<<2048, 256, 0, stream>>>(qf0, qf1, kvim, rden, attn);
  splitT_kernel<<<1024, 256, 0, stream>>>(Wo, wto_h, wto_l);
  split_kernel<<<8192, 256, 0, stream>>>(attn, attnh, attnl, 2097152);
  gemm_bf16<1><<<512, 256, 0, stream>>>(attnh, attnl, wto_h, wto_l, bo, out, nullptr);
}

// Round 5
// 344.830 us; speedup vs baseline: 3.4277x; 1.7584x over previous
//
#include <hip/hip_runtime.h>
#include <hip/hip_bf16.h>
#include <cstdint>

// Performer (FAVOR+) non-causal attention. B=4 S=4096 D=512 H=8 KD=64 R=256.
// R5: kv_partial -> MFMA (kf_kernel + kv_gemm + kvred). Whole pipeline on MFMA.
constexpr int B = 4, S = 4096, D = 512, H = 8, KD = 64, R = 256;
constexpr float EPS = 1e-3f;

typedef unsigned short u16;
typedef __attribute__((ext_vector_type(8))) short bf16x8;
typedef __attribute__((ext_vector_type(4))) float f32x4;

// ws layout (float-slot offsets); peak 30.8M slots < proven 34.23M (137 MB)
constexpr size_t OFF_QIM   = 0;          // qim (4.2M); attnh later
constexpr size_t OFF_KIM   = 4194304;    // kim (4.2M); kvp later; attnl later
constexpr size_t OFF_VTIM  = 8388608;    // vtim (4.2M); Wo splits later
constexpr size_t OFF_KFT   = 12582912;   // Wq/k/v splits head; kfT (16.8M); qf later
constexpr size_t OFF_RFIM  = 29360128;   // 8192
constexpr size_t OFF_KSUM  = 29368320;   // 8192
constexpr size_t OFF_RDEN  = 29376512;   // 131072
constexpr size_t OFF_KVIM  = 29507584;   // 262144
constexpr size_t OFF_KSUMP = 29769728;   // 1048576 (32bh x 128 x 256r)

__device__ __forceinline__ u16 f2bf(float f) {
  unsigned u = __float_as_uint(f);
  return (u16)((u + 0x7FFF + ((u >> 16) & 1)) >> 16);  // RNE
}
__device__ __forceinline__ float bf2f(u16 b) {
  return __uint_as_float(((unsigned)b) << 16);
}
__device__ __forceinline__ void gl_lds16(const void* g, void* l) {
  __builtin_amdgcn_global_load_lds(
      (const __attribute__((address_space(1))) unsigned int*)g,
      (__attribute__((address_space(3))) unsigned int*)l, 16, 0, 0);
}
__device__ __forceinline__ f32x4 mfma16(bf16x8 a, bf16x8 b, f32x4 c) {
  return __builtin_amdgcn_mfma_f32_16x16x32_bf16(a, b, c, 0, 0, 0);
}

// ---------- preprocessing ----------
__global__ __launch_bounds__(256) void split_kernel(const float* __restrict__ in,
                                                    u16* __restrict__ hi,
                                                    u16* __restrict__ lo, int n4) {
  int i = blockIdx.x * 256 + threadIdx.x;
  if (i >= n4) return;
  float4 v = ((const float4*)in)[i];
  u16 h0 = f2bf(v.x), h1 = f2bf(v.y), h2 = f2bf(v.z), h3 = f2bf(v.w);
  u16 l0 = f2bf(v.x - bf2f(h0)), l1 = f2bf(v.y - bf2f(h1));
  u16 l2 = f2bf(v.z - bf2f(h2)), l3 = f2bf(v.w - bf2f(h3));
  ((ushort4*)hi)[i] = make_ushort4(h0, h1, h2, h3);
  ((ushort4*)lo)[i] = make_ushort4(l0, l1, l2, l3);
}

__global__ __launch_bounds__(256) void splitT_kernel(const float* __restrict__ W,
                                                     u16* __restrict__ hi,
                                                     u16* __restrict__ lo) {
  int i = blockIdx.x * 256 + threadIdx.x;  // [n][k]
  int n = i >> 9, k = i & 511;
  float v = W[(size_t)k * 512 + n];
  u16 h = f2bf(v);
  hi[i] = h;
  lo[i] = f2bf(v - bf2f(h));
}

// rfim bf16 B-image [256 r][64 d], 16B-slot swizzle key (r&7)
__global__ __launch_bounds__(256) void rft_kernel(const float* __restrict__ rf,
                                                  u16* __restrict__ rfim) {
  int i = blockIdx.x * 256 + threadIdx.x;  // 16384
  int r2 = i >> 6, d2 = i & 63;
  float v = rf[r2 * KD + d2] * 0.125f;
  rfim[r2 * 64 + (((d2 >> 3) ^ (r2 & 7)) << 3) + (d2 & 7)] = f2bf(v);
}

// ---------- split-bf16 3-pass GEMM (128x128 tile) ----------
// OMODE 1: fp32 + bias. 2: A-image (per-bh [s][64], key s&7). 3: vT-image
// (per-bh [64 d][4096 s], 16B-slot key (d>>1)&3, pre-baked for kv_gemm).
template <int OMODE>
__global__ __launch_bounds__(256) void gemm_bf16(const u16* __restrict__ Ah,
                                                 const u16* __restrict__ Al,
                                                 const u16* __restrict__ Bh,
                                                 const u16* __restrict__ Bl,
                                                 const float* __restrict__ bias,
                                                 float* __restrict__ C,
                                                 u16* __restrict__ Cimg) {
  __shared__ alignas(16) u16 lds[4][4096];
  const int t = threadIdx.x, lane = t & 63, w = t >> 6;
  const int bm = (int)(blockIdx.x >> 2) * 128;
  const int bn = (int)(blockIdx.x & 3) * 128;
  const int wr = w >> 1, wc = w & 1;
  const int srow = lane >> 2;
  const int scol = (((lane & 3) ^ ((lane >> 3) & 3)) << 3);
  const int fm = lane & 15, fg = lane >> 4;
  const int foff = fm * 64 + (((fg ^ ((fm >> 1) & 3)) & 3) << 4);
  f32x4 acc[4][4];
#pragma unroll
  for (int i = 0; i < 4; ++i)
#pragma unroll
    for (int j = 0; j < 4; ++j) acc[i][j] = {0.f, 0.f, 0.f, 0.f};

  const int rg = w * 32;
  for (int k0 = 0; k0 < 512; k0 += 32) {
    __syncthreads();
#pragma unroll
    for (int L = 0; L < 2; ++L) {
      const int rloc = rg + L * 16;
      const size_t ga = (((size_t)(bm + rloc + srow)) << 9) + (size_t)(k0 + scol);
      const size_t gb = (((size_t)(bn + rloc + srow)) << 9) + (size_t)(k0 + scol);
      char* ldst = (char*)lds + rloc * 64;
      gl_lds16(Ah + ga, ldst);
      gl_lds16(Al + ga, ldst + 8192);
      gl_lds16(Bh + gb, ldst + 16384);
      gl_lds16(Bl + gb, ldst + 24576);
    }
    __syncthreads();
    bf16x8 ah[4], al[4], bh[4], bl[4];
#pragma unroll
    for (int i = 0; i < 4; ++i) {
      const int ro = (wr * 64 + 16 * i) * 64 + foff;
      const int co = (wc * 64 + 16 * i) * 64 + foff;
      ah[i] = *(const bf16x8*)((const char*)lds + ro);
      al[i] = *(const bf16x8*)((const char*)lds + 8192 + ro);
      bh[i] = *(const bf16x8*)((const char*)lds + 16384 + co);
      bl[i] = *(const bf16x8*)((const char*)lds + 24576 + co);
    }
#pragma unroll
    for (int i = 0; i < 4; ++i)
#pragma unroll
      for (int j = 0; j < 4; ++j) {
        acc[i][j] = mfma16(ah[i], bh[j], acc[i][j]);
        acc[i][j] = mfma16(ah[i], bl[j], acc[i][j]);
        acc[i][j] = mfma16(al[i], bh[j], acc[i][j]);
      }
  }
  const int cn = bn + wc * 64 + fm;
  const int rm0 = bm + wr * 64 + fg * 4;
#pragma unroll
  for (int j = 0; j < 4; ++j) {
#pragma unroll
    for (int i = 0; i < 4; ++i)
#pragma unroll
      for (int r = 0; r < 4; ++r) {
        const int mg = rm0 + 16 * i + r;
        const int n = cn + 16 * j;
        if (OMODE == 2) {
          const int bh_ = (mg >> 12) * 8 + (n >> 6);
          const int sl = mg & 4095, d = n & 63;
          Cimg[(size_t)bh_ * 262144 + sl * 64 + (((d >> 3) ^ (sl & 7)) << 3) + (d & 7)] =
              f2bf(acc[i][j][r]);
        } else if (OMODE == 3) {
          const int bh_ = (mg >> 12) * 8 + (n >> 6);
          const int ss = mg & 4095, d = n & 63;
          Cimg[(size_t)bh_ * 262144 + d * 4096 + (ss & ~31) +
               (((((ss >> 3) & 3)) ^ ((d >> 1) & 3)) << 3) + (ss & 7)] =
              f2bf(acc[i][j][r]);
        } else {
          C[(size_t)mg * 512 + n] = acc[i][j][r] + bias[n];
        }
      }
  }
}

// ---------- kf features: proj MFMA + rowmax/exp; writes kfT image + ksum partials
// grid: 32 bh * 32 s-tiles(128). kfT per bh: [256 r][4096 s], slot key (r>>1)&3.
__global__ __launch_bounds__(256) void kf_kernel(const u16* __restrict__ kim,
                                                 const u16* __restrict__ rfim,
                                                 u16* __restrict__ kft,
                                                 float* __restrict__ ksump) {
  __shared__ alignas(16) u16 lds_rf[16384];  // [256 r][64 d] image
  __shared__ alignas(16) u16 lds_k[8192];    // [128 s][64 d] image
  const int t = threadIdx.x, lane = t & 63, w = t >> 6;
  const int bid = blockIdx.x;
  const int bh = bid >> 5, stile = bid & 31;
  const int fm = lane & 15, fg = lane >> 4;
  const u16* ksrc = kim + (size_t)bh * 262144 + (size_t)stile * 8192;
#pragma unroll
  for (int rnd = 0; rnd < 8; ++rnd)
    gl_lds16(rfim + rnd * 2048 + w * 512 + lane * 8,
             (char*)lds_rf + rnd * 4096 + w * 1024 + lane * 16);
#pragma unroll
  for (int rnd = 0; rnd < 4; ++rnd)
    gl_lds16(ksrc + rnd * 2048 + w * 512 + lane * 8,
             (char*)lds_k + rnd * 4096 + w * 1024 + lane * 16);
  __syncthreads();
  f32x4 acc[2][16];
#pragma unroll
  for (int i = 0; i < 2; ++i)
#pragma unroll
    for (int j = 0; j < 16; ++j) acc[i][j] = {0.f, 0.f, 0.f, 0.f};
#pragma unroll
  for (int c = 0; c < 2; ++c) {
    const int so = (((c * 4 + fg) ^ (fm & 7)) << 4);
    bf16x8 a[2];
#pragma unroll
    for (int i = 0; i < 2; ++i)
      a[i] = *(const bf16x8*)((const char*)lds_k + (w * 32 + 16 * i + fm) * 128 + so);
#pragma unroll
    for (int j = 0; j < 16; ++j) {
      bf16x8 b = *(const bf16x8*)((const char*)lds_rf + (16 * j + fm) * 128 + so);
      acc[0][j] = mfma16(a[0], b, acc[0][j]);
      acc[1][j] = mfma16(a[1], b, acc[1][j]);
    }
  }
  float psum[16];
#pragma unroll
  for (int j = 0; j < 16; ++j) psum[j] = 0.f;
  u16* kbase = kft + (size_t)bh * 1048576;
  const int schunk = stile * 128 + w * 32;  // s & ~31
#pragma unroll
  for (int i = 0; i < 2; ++i) {
    float m2[4] = {-1e30f, -1e30f, -1e30f, -1e30f};
#pragma unroll
    for (int j = 0; j < 16; ++j)
#pragma unroll
      for (int r = 0; r < 4; ++r) m2[r] = fmaxf(m2[r], acc[i][j][r]);
#pragma unroll
    for (int r = 0; r < 4; ++r)
#pragma unroll
      for (int off = 1; off < 16; off <<= 1) m2[r] = fmaxf(m2[r], __shfl_xor(m2[r], off));
#pragma unroll
    for (int j = 0; j < 16; ++j) {
      const int rr = 16 * j + fm;
      const int key = (rr >> 1) & 3;
#pragma unroll
      for (int r = 0; r < 4; ++r) {
        float e = __expf(acc[i][j][r] - m2[r]) + EPS;
        psum[j] += e;
        const int slo = 16 * i + fg * 4 + r;  // s & 31
        kbase[(size_t)rr * 4096 + schunk +
              ((((slo >> 3) & 3) ^ key) << 3) + (slo & 7)] = f2bf(e);
      }
    }
  }
#pragma unroll
  for (int j = 0; j < 16; ++j) {
    float s = psum[j];
    s += __shfl_xor(s, 16);
    s += __shfl_xor(s, 32);
    if (fg == 0)
      ksump[(size_t)(((bh * 32 + stile) * 4 + w)) * 256 + 16 * j + fm] = s;
  }
}

// ---------- kv GEMM: kvp[ch][bh][r][d] = sum_{s in chunk} kfT[r][s]*vT[d][s]
// grid: 32 bh * 8 chunks(512 s). 4 waves; wave w owns r in [64w, 64w+64).
__global__ __launch_bounds__(256) void kv_gemm(const u16* __restrict__ kft,
                                               const u16* __restrict__ vtim,
                                               float* __restrict__ kvp) {
  __shared__ alignas(16) u16 lds_a[8192];  // [256 r][32 s] 16KB
  __shared__ alignas(16) u16 lds_b[2048];  // [64 d][32 s] 4KB
  const int t = threadIdx.x, lane = t & 63, w = t >> 6;
  const int bid = blockIdx.x;
  const int bh = bid >> 3, ch = bid & 7;
  const int fm = lane & 15, fg = lane >> 4;
  const int foff = (fg ^ ((fm >> 1) & 3)) << 4;
  const u16* asrc = kft + (size_t)bh * 1048576 + ch * 512;
  const u16* bsrc = vtim + (size_t)bh * 262144 + ch * 512;
  f32x4 acc[4][4];
#pragma unroll
  for (int i = 0; i < 4; ++i)
#pragma unroll
    for (int j = 0; j < 4; ++j) acc[i][j] = {0.f, 0.f, 0.f, 0.f};
  const int lr = lane >> 2, ls = lane & 3;  // staging: row-of-16, 16B slot
  for (int k0 = 0; k0 < 512; k0 += 32) {
    __syncthreads();
#pragma unroll
    for (int rnd = 0; rnd < 4; ++rnd) {
      const int o = rnd * 4 + w;  // A rows [o*16, o*16+16)
      gl_lds16(asrc + (size_t)(o * 16 + lr) * 4096 + k0 + ls * 8,
               (char*)lds_a + o * 1024);
    }
    gl_lds16(bsrc + (size_t)(w * 16 + lr) * 4096 + k0 + ls * 8,
             (char*)lds_b + w * 1024);
    __syncthreads();
    bf16x8 a[4], b[4];
#pragma unroll
    for (int i = 0; i < 4; ++i) {
      a[i] = *(const bf16x8*)((const char*)lds_a + (w * 64 + 16 * i + fm) * 64 + foff);
      b[i] = *(const bf16x8*)((const char*)lds_b + (16 * i + fm) * 64 + foff);
    }
#pragma unroll
    for (int i = 0; i < 4; ++i)
#pragma unroll
      for (int j = 0; j < 4; ++j) acc[i][j] = mfma16(a[i], b[j], acc[i][j]);
  }
  float* o = kvp + (size_t)ch * 524288 + (size_t)bh * 16384;
#pragma unroll
  for (int i = 0; i < 4; ++i)
#pragma unroll
    for (int j = 0; j < 4; ++j)
#pragma unroll
      for (int r = 0; r < 4; ++r) {
        const int rr = w * 64 + 16 * i + fg * 4 + r;
        const int d = 16 * j + fm;
        o[rr * 64 + d] = acc[i][j][r];
      }
}

// ---------- reduce: kvp(8) -> kvim B-image; ksump(128) -> ksum ----------
__global__ __launch_bounds__(256) void kvred_kernel(const float* __restrict__ kvp,
                                                    const float* __restrict__ ksump,
                                                    u16* __restrict__ kvim,
                                                    float* __restrict__ ksum) {
  const int i = blockIdx.x * 256 + threadIdx.x;  // 524288
  const int bh = i >> 14, rd = i & 16383;
  const int r = rd >> 6, dd = rd & 63;
  float s = 0.f;
#pragma unroll
  for (int c = 0; c < 8; ++c) s += kvp[(size_t)c * 524288 + i];
  kvim[(size_t)bh * 16384 + dd * 256 + (((r >> 3) ^ (dd & 7)) << 3) + (r & 7)] = f2bf(s);
  if (i < B * H * R) {
    const int bh2 = i >> 8, r2 = i & 255;
    float ss = 0.f;
    for (int c = 0; c < 128; ++c) ss += ksump[(size_t)(bh2 * 128 + c) * 256 + r2];
    ksum[i] = ss;
  }
}

// ---------- qf features + den ----------
__global__ __launch_bounds__(256) void qproj_kernel(const u16* __restrict__ qim,
                                                    const u16* __restrict__ rfim,
                                                    const float* __restrict__ ksum,
                                                    u16* __restrict__ qf,
                                                    float* __restrict__ rden) {
  __shared__ alignas(16) u16 lds_rf[16384];
  __shared__ alignas(16) u16 lds_q[8192];
  const int t = threadIdx.x, lane = t & 63, w = t >> 6;
  const int bid = blockIdx.x;
  const int bh = bid >> 5, stile = bid & 31;
  const int fm = lane & 15, fg = lane >> 4;
  u16* qfb = qf + (size_t)bh * 1048576;
  const u16* qsrc = qim + (size_t)bh * 262144 + (size_t)stile * 8192;
#pragma unroll
  for (int rnd = 0; rnd < 8; ++rnd)
    gl_lds16(rfim + rnd * 2048 + w * 512 + lane * 8,
             (char*)lds_rf + rnd * 4096 + w * 1024 + lane * 16);
#pragma unroll
  for (int rnd = 0; rnd < 4; ++rnd)
    gl_lds16(qsrc + rnd * 2048 + w * 512 + lane * 8,
             (char*)lds_q + rnd * 4096 + w * 1024 + lane * 16);
  __syncthreads();
  f32x4 acc[2][16];
#pragma unroll
  for (int i = 0; i < 2; ++i)
#pragma unroll
    for (int j = 0; j < 16; ++j) acc[i][j] = {0.f, 0.f, 0.f, 0.f};
#pragma unroll
  for (int c = 0; c < 2; ++c) {
    const int so = (((c * 4 + fg) ^ (fm & 7)) << 4);
    bf16x8 a[2];
#pragma unroll
    for (int i = 0; i < 2; ++i)
      a[i] = *(const bf16x8*)((const char*)lds_q + (w * 32 + 16 * i + fm) * 128 + so);
#pragma unroll
    for (int j = 0; j < 16; ++j) {
      bf16x8 b = *(const bf16x8*)((const char*)lds_rf + (16 * j + fm) * 128 + so);
      acc[0][j] = mfma16(a[0], b, acc[0][j]);
      acc[1][j] = mfma16(a[1], b, acc[1][j]);
    }
  }
  float ksl[16];
#pragma unroll
  for (int j = 0; j < 16; ++j) ksl[j] = ksum[bh * 256 + 16 * j + fm];
#pragma unroll
  for (int i = 0; i < 2; ++i) {
    float m2[4] = {-1e30f, -1e30f, -1e30f, -1e30f};
#pragma unroll
    for (int j = 0; j < 16; ++j)
#pragma unroll
      for (int r = 0; r < 4; ++r) m2[r] = fmaxf(m2[r], acc[i][j][r]);
#pragma unroll
    for (int r = 0; r < 4; ++r)
#pragma unroll
      for (int off = 1; off < 16; off <<= 1) m2[r] = fmaxf(m2[r], __shfl_xor(m2[r], off));
    float den[4] = {0.f, 0.f, 0.f, 0.f};
    const int s0 = stile * 128 + w * 32 + 16 * i + fg * 4;
#pragma unroll
    for (int j = 0; j < 16; ++j) {
      const int rr = fm + 16 * j;
#pragma unroll
      for (int r = 0; r < 4; ++r) {
        float e = __expf(acc[i][j][r] - m2[r]) + EPS;
        den[r] = fmaf(e, ksl[j], den[r]);
        const int s = s0 + r;
        qfb[(size_t)s * 256 + (((rr >> 3) ^ (s & 7)) << 3) + (rr & 7)] = f2bf(e);
      }
    }
#pragma unroll
    for (int r = 0; r < 4; ++r) {
#pragma unroll
      for (int off = 1; off < 16; off <<= 1) den[r] += __shfl_xor(den[r], off);
      if (fm == 0) rden[bh * 4096 + s0 + r] = 1.0f / (den[r] + EPS);
    }
  }
}

// ---------- num GEMM: attn = (qf @ kv) * rden -> attnh/attnl bf16 split ----------
__global__ __launch_bounds__(256) void num_gemm(const u16* __restrict__ qf,
                                                const u16* __restrict__ kvim,
                                                const float* __restrict__ rden,
                                                u16* __restrict__ attnh,
                                                u16* __restrict__ attnl) {
  __shared__ alignas(16) u16 lds_kv[16384];
  __shared__ alignas(16) u16 lds_qf[16384];
  const int t = threadIdx.x, lane = t & 63, w = t >> 6;
  const int bid = blockIdx.x;
  const int bh = bid >> 6, stile = bid & 63;
  const int fm = lane & 15, fg = lane >> 4;
  const u16* qfb = qf + (size_t)bh * 1048576 + (size_t)stile * 16384;
  const u16* kvsrc = kvim + (size_t)bh * 16384;
#pragma unroll
  for (int rnd = 0; rnd < 8; ++rnd) {
    gl_lds16(kvsrc + rnd * 2048 + w * 512 + lane * 8,
             (char*)lds_kv + rnd * 4096 + w * 1024 + lane * 16);
    gl_lds16(qfb + rnd * 2048 + w * 512 + lane * 8,
             (char*)lds_qf + rnd * 4096 + w * 1024 + lane * 16);
  }
  __syncthreads();
  f32x4 acc[4];
#pragma unroll
  for (int j = 0; j < 4; ++j) acc[j] = {0.f, 0.f, 0.f, 0.f};
#pragma unroll
  for (int c = 0; c < 8; ++c) {
    const int so = (((c * 4 + fg) ^ (fm & 7)) << 4);
    bf16x8 a = *(const bf16x8*)((const char*)lds_qf + (w * 16 + fm) * 512 + so);
#pragma unroll
    for (int j = 0; j < 4; ++j) {
      bf16x8 b = *(const bf16x8*)((const char*)lds_kv + (16 * j + fm) * 512 + so);
      acc[j] = mfma16(a, b, acc[j]);
    }
  }
  const int b = bh >> 3, h = bh & 7;
  const int s0 = stile * 64 + w * 16 + fg * 4;
  float rd4[4];
#pragma unroll
  for (int r = 0; r < 4; ++r) rd4[r] = rden[bh * 4096 + s0 + r];
#pragma unroll
  for (int j = 0; j < 4; ++j)
#pragma unroll
    for (int r = 0; r < 4; ++r) {
      const size_t idx = (size_t)(b * 4096 + s0 + r) * 512 + h * 64 + fm + 16 * j;
      float o = acc[j][r] * rd4[r];
      u16 hh = f2bf(o);
      attnh[idx] = hh;
      attnl[idx] = f2bf(o - bf2f(hh));
    }
}

extern "C" void kernel_launch(void* const* d_in, const int* in_sizes, int n_in,
                              void* d_out, int out_size, void* d_ws, size_t ws_size,
                              hipStream_t stream) {
  const float* x  = (const float*)d_in[0];
  const float* Wq = (const float*)d_in[1];
  const float* Wk = (const float*)d_in[2];
  const float* Wv = (const float*)d_in[3];
  const float* rf = (const float*)d_in[4];
  const float* Wo = (const float*)d_in[5];
  const float* bo = (const float*)d_in[6];
  float* out = (float*)d_out;
  float* ws = (float*)d_ws;

  u16*   qim   = (u16*)(ws + OFF_QIM);
  u16*   kim   = (u16*)(ws + OFF_KIM);
  u16*   vtim  = (u16*)(ws + OFF_VTIM);
  u16*   kft   = (u16*)(ws + OFF_KFT);   // W-qkv splits live here first
  u16*   rfim  = (u16*)(ws + OFF_RFIM);
  float* ksum  = ws + OFF_KSUM;
  float* rden  = ws + OFF_RDEN;
  u16*   kvim  = (u16*)(ws + OFF_KVIM);
  float* ksump = ws + OFF_KSUMP;

  u16* xh = (u16*)d_out;                 // d_out dead until final GEMM
  u16* xl = xh + 8388608;
  u16* wt = (u16*)(ws + OFF_KFT);        // dead before kf_kernel writes kft
  u16 *wtq_h = wt,           *wtq_l = wt + 262144;
  u16 *wtk_h = wt + 524288,  *wtk_l = wt + 786432;
  u16 *wtv_h = wt + 1048576, *wtv_l = wt + 1310720;
  float* kvp = ws + OFF_KIM;             // kim dead after kf_kernel
  u16* qf    = (u16*)(ws + OFF_KFT);     // kft dead after kv_gemm
  u16* wto_h = (u16*)(ws + OFF_VTIM);    // vtim dead after kv_gemm
  u16* wto_l = wto_h + 262144;
  u16* attnh = (u16*)(ws + OFF_QIM);     // qim dead after qproj
  u16* attnl = (u16*)(ws + OFF_KIM);     // kvp dead after kvred

  split_kernel<<<8192, 256, 0, stream>>>(x, xh, xl, 2097152);
  splitT_kernel<<<1024, 256, 0, stream>>>(Wq, wtq_h, wtq_l);
  splitT_kernel<<<1024, 256, 0, stream>>>(Wk, wtk_h, wtk_l);
  splitT_kernel<<<1024, 256, 0, stream>>>(Wv, wtv_h, wtv_l);
  rft_kernel<<<64, 256, 0, stream>>>(rf, rfim);
  gemm_bf16<2><<<512, 256, 0, stream>>>(xh, xl, wtk_h, wtk_l, nullptr, nullptr, kim);
  gemm_bf16<3><<<512, 256, 0, stream>>>(xh, xl, wtv_h, wtv_l, nullptr, nullptr, vtim);
  gemm_bf16<2><<<512, 256, 0, stream>>>(xh, xl, wtq_h, wtq_l, nullptr, nullptr, qim);
  kf_kernel<<<1024, 256, 0, stream>>>(kim, rfim, kft, ksump);
  kv_gemm<<<256, 256, 0, stream>>>(kft, vtim, kvp);
  kvred_kernel<<<2048, 256, 0, stream>>>(kvp, ksump, kvim, ksum);
  qproj_kernel<<<1024, 256, 0, stream>>>(qim, rfim, ksum, qf, rden);
  num_gemm<<<2048, 256, 0, stream>>>(qf, kvim, rden, attnh, attnl);
  splitT_kernel<<<1024, 256, 0, stream>>>(Wo, wto_h, wto_l);
  gemm_bf16<1><<<512, 256, 0, stream>>>(attnh, attnl, wto_h, wto_l, bo, out, nullptr);
}